// Round 1
// baseline (908.658 us; speedup 1.0000x reference)
//
#include <hip/hip_runtime.h>
#include <math.h>

#define NW 24
#define NB 8
#define SSIZE (1u << 24)

// Flat index convention (matches jnp reshape(-1) of shape (2,)*24):
//   wire w <-> bit b = 23 - w  (wire 0 = MSB).
// Per circuit block k: RY(theta[k][w]) on every wire, then CNOT(w, w+1) for
// w = 0..22, i.e. in bit terms CNOT(ctrl=c, tgt=c-1) for c = 23 down to 1.
//
// ws layout (floats): [0] = sum accumulator,
//                     [64  + k*24 + w] = cos(theta/2),
//                     [256 + k*24 + w] = sin(theta/2).

__global__ void k_prep(const float* __restrict__ ang, float* __restrict__ ws) {
    int t = threadIdx.x;
    if (t == 0) ws[0] = 0.0f;
    if (t < NB * NW) {
        float a = 0.5f * ang[t];
        ws[64 + t]  = cosf(a);
        ws[256 + t] = sinf(a);
    }
}

// State after block 0 from |0..0>: amp(i) = prod_b phi_{wire 23-b}( bit b of (i ^ (i>>1)) )
__global__ void k_init(float* __restrict__ st, const float* __restrict__ ws) {
    const float* C = ws + 64;    // block 0 tables
    const float* S = ws + 256;
    unsigned q = blockIdx.x * blockDim.x + threadIdx.x;   // float4 index
    unsigned i = q << 2;
    unsigned jb = i ^ (i >> 1);
    float P = 1.0f;
#pragma unroll
    for (int b = 2; b < 24; ++b) {
        int w = 23 - b;
        P *= ((jb >> b) & 1) ? S[w] : C[w];
    }
    float4 v;
    float* vv = &v.x;
#pragma unroll
    for (int d = 0; d < 4; ++d) {
        unsigned ii = i + d;
        unsigned j = ii ^ (ii >> 1);
        float f1 = ((j >> 1) & 1) ? S[22] : C[22];
        float f0 = (j & 1)        ? S[23] : C[23];
        vv[d] = P * f1 * f0;
    }
    reinterpret_cast<float4*>(st)[q] = v;
}

// Pass A: tile = global bits 0..13 (contiguous, 16K floats). blockIdx = global bits 14..23.
// Gates: stage b=13: RY(b13) + CNOT(ctrl = fixed bit14 = m&1, tgt b13)
//        stage b=12..0: RY(b) + CNOT(b+1, b)   (chain gates c = 13..1)
__global__ __launch_bounds__(512) void k_passA(float* __restrict__ st,
                                               const float* __restrict__ ws, int k) {
    __shared__ float T[16384];
    const unsigned m = blockIdx.x;
    const unsigned tid = threadIdx.x;
    const float* C = ws + 64 + k * 24;
    const float* S = ws + 256 + k * 24;
    float cc[14], sv[14];
#pragma unroll
    for (int b = 0; b < 14; ++b) { cc[b] = C[23 - b]; sv[b] = S[23 - b]; }

    float4* T4 = reinterpret_cast<float4*>(T);
    float4* G4 = reinterpret_cast<float4*>(st);
    const unsigned base4 = m << 12;
#pragma unroll
    for (unsigned e = 0; e < 8; ++e) T4[tid + e * 512] = G4[base4 + tid + e * 512];
    __syncthreads();

    // stage b = 13: RY + fixed-control CNOT(14,13)
    {
        const float c = cc[13], s = sv[13];
        const bool f = (m & 1u);
#pragma unroll
        for (unsigned e = 0; e < 16; ++e) {
            unsigned p  = tid + e * 512;     // bits 0..12
            unsigned i1 = p | 8192u;
            float a0 = T[p], a1 = T[i1];
            float w0 = c * a0 - s * a1;
            float w1 = s * a0 + c * a1;
            T[p]  = f ? w1 : w0;
            T[i1] = f ? w0 : w1;
        }
        __syncthreads();
    }
#pragma unroll
    for (int b = 12; b >= 0; --b) {
        const float c = cc[b], s = sv[b];
        const unsigned lom = (1u << b) - 1u;
#pragma unroll
        for (unsigned e = 0; e < 8; ++e) {
            unsigned q   = tid + e * 512;    // granule over bits (b+1, b)
            unsigned lo  = q & lom;
            unsigned i00 = ((q >> b) << (b + 2)) | lo;
            unsigned i01 = i00 | (1u << b);
            unsigned i10 = i00 | (2u << b);
            unsigned i11 = i10 | (1u << b);
            float v00 = T[i00], v01 = T[i01], v10 = T[i10], v11 = T[i11];
            T[i00] = c * v00 - s * v01;       // RY(b), ctrl(b+1)=0 half
            T[i01] = s * v00 + c * v01;
            T[i10] = s * v10 + c * v11;       // RY(b) then CNOT(b+1,b) swap
            T[i11] = c * v10 - s * v11;
        }
        __syncthreads();
    }
#pragma unroll
    for (unsigned e = 0; e < 8; ++e) G4[base4 + tid + e * 512] = T4[tid + e * 512];
}

// Pass B: tile = global bits {0..3} u {14..23}. blockIdx m = global bits 4..13.
// local bit j: 0..3 -> global 0..3 (idle), 4..13 -> global 14..23.
// Gates: RY(local 13) alone (= global 23), then stages j=12..4: RY(j) + CNOT(j+1, j)
//        (= chain gates c = 23..15).
__global__ __launch_bounds__(512) void k_passB(float* __restrict__ st,
                                               const float* __restrict__ ws, int k) {
    __shared__ float T[16384];
    const unsigned m = blockIdx.x;
    const unsigned tid = threadIdx.x;
    const float* C = ws + 64 + k * 24;
    const float* S = ws + 256 + k * 24;
    float cc[14], sv[14];
#pragma unroll
    for (int j = 4; j < 14; ++j) { cc[j] = C[13 - j]; sv[j] = S[13 - j]; }

    float4* T4 = reinterpret_cast<float4*>(T);
    float4* G4 = reinterpret_cast<float4*>(st);
    // local float4 e = (h<<2)|l4  <->  global float4 = (h<<12)|(m<<2)|l4
#pragma unroll
    for (unsigned i = 0; i < 8; ++i) {
        unsigned e = tid + i * 512;
        unsigned h = e >> 2, l4 = e & 3u;
        T4[e] = G4[(h << 12) | (m << 2) | l4];
    }
    __syncthreads();
    {   // RY on local bit 13 (global 23, wire 0)
        const float c = cc[13], s = sv[13];
#pragma unroll
        for (unsigned i = 0; i < 16; ++i) {
            unsigned p = tid + i * 512;
            unsigned i1 = p | 8192u;
            float a0 = T[p], a1 = T[i1];
            T[p]  = c * a0 - s * a1;
            T[i1] = s * a0 + c * a1;
        }
        __syncthreads();
    }
#pragma unroll
    for (int j = 12; j >= 4; --j) {
        const float c = cc[j], s = sv[j];
        const unsigned lom = (1u << j) - 1u;
#pragma unroll
        for (unsigned i = 0; i < 8; ++i) {
            unsigned q   = tid + i * 512;
            unsigned lo  = q & lom;
            unsigned i00 = ((q >> j) << (j + 2)) | lo;
            unsigned i01 = i00 | (1u << j);
            unsigned i10 = i00 | (2u << j);
            unsigned i11 = i10 | (1u << j);
            float v00 = T[i00], v01 = T[i01], v10 = T[i10], v11 = T[i11];
            T[i00] = c * v00 - s * v01;
            T[i01] = s * v00 + c * v01;
            T[i10] = s * v10 + c * v11;
            T[i11] = c * v10 - s * v11;
        }
        __syncthreads();
    }
#pragma unroll
    for (unsigned i = 0; i < 8; ++i) {
        unsigned e = tid + i * 512;
        unsigned h = e >> 2, l4 = e & 3u;
        G4[(h << 12) | (m << 2) | l4] = T4[e];
    }
}

// x = (0.6*tanh(0.1*2^23*v^2))^0.15, in place; accumulate sum into ws[0].
__global__ void k_x(float* __restrict__ st, float* __restrict__ ws) {
    __shared__ float wsum[8];
    unsigned tid = threadIdx.x;
    unsigned idx = blockIdx.x * blockDim.x + tid;
    unsigned stride = gridDim.x * blockDim.x;
    float4* G4 = reinterpret_cast<float4*>(st);
    float lsum = 0.f;
    for (unsigned q = idx; q < (SSIZE / 4); q += stride) {
        float4 v = G4[q];
        float* vv = &v.x;
        float4 r;
        float* rr = &r.x;
#pragma unroll
        for (int d = 0; d < 4; ++d) {
            float p = vv[d] * vv[d];
            float t = tanhf(838860.8f * p);          // GAMMA * 2^23
            float x = powf(0.6f * t, 0.15f);         // BETA, ALPHA
            rr[d] = x;
            lsum += x;
        }
        G4[q] = r;
    }
#pragma unroll
    for (int o = 32; o > 0; o >>= 1) lsum += __shfl_down(lsum, o, 64);
    if ((tid & 63u) == 0) wsum[tid >> 6] = lsum;
    __syncthreads();
    if (tid == 0) {
        float b = 0.f;
        int nwav = blockDim.x / 64;
        for (int i = 0; i < nwav; ++i) b += wsum[i];
        atomicAdd(ws, b);
    }
}

__global__ void k_final(float* __restrict__ st, const float* __restrict__ ws) {
    unsigned idx = blockIdx.x * blockDim.x + threadIdx.x;
    unsigned stride = gridDim.x * blockDim.x;
    float mean = ws[0] * (1.0f / 16777216.0f);
    float4* G4 = reinterpret_cast<float4*>(st);
    for (unsigned q = idx; q < (SSIZE / 4); q += stride) {
        float4 v = G4[q];
        v.x -= mean; v.y -= mean; v.z -= mean; v.w -= mean;
        G4[q] = v;
    }
}

extern "C" void kernel_launch(void* const* d_in, const int* in_sizes, int n_in,
                              void* d_out, int out_size, void* d_ws, size_t ws_size,
                              hipStream_t stream) {
    const float* ang = (const float*)d_in[0];   // [8][24] float32
    float* st = (float*)d_out;                  // state lives in d_out (64 MB), in place
    float* ws = (float*)d_ws;                   // sum + cos/sin tables

    k_prep<<<1, 256, 0, stream>>>(ang, ws);
    k_init<<<16384, 256, 0, stream>>>(st, ws);
    for (int k = 1; k < NB; ++k) {
        k_passB<<<1024, 512, 0, stream>>>(st, ws, k);
        k_passA<<<1024, 512, 0, stream>>>(st, ws, k);
    }
    k_x<<<4096, 256, 0, stream>>>(st, ws);
    k_final<<<4096, 256, 0, stream>>>(st, ws);
}

// Round 3
// 617.046 us; speedup vs baseline: 1.4726x; 1.4726x over previous
//
#include <hip/hip_runtime.h>

#define NW 24
#define NB 8
#define SSIZE (1u << 24)

// Flat index convention (matches jnp reshape(-1) of shape (2,)*24):
//   wire w <-> bit b = 23 - w  (wire 0 = MSB).
// Per circuit block k: RY(theta[k][w]) on every wire, then CNOT chain:
// in bit terms CNOT(ctrl=c, tgt=c-1) for c = 23 down to 1, applied as
// "stage b" = RY(b) + CNOT(b+1, b), descending b (valid: RY(b) commutes
// with CNOTs on higher bits).
//
// ws layout (floats): [0] = sum accumulator,
//                     [64  + k*24 + w] = cos(theta/2),
//                     [256 + k*24 + w] = sin(theta/2).

__global__ void k_prep(const float* __restrict__ ang, float* __restrict__ ws) {
    int t = threadIdx.x;
    if (t == 0) ws[0] = 0.0f;
    if (t < NB * NW) {
        float a = 0.5f * ang[t];
        ws[64 + t]  = __builtin_cosf(a);
        ws[256 + t] = __builtin_sinf(a);
    }
}

// State after block 0 from |0..0>: amp(i) = prod_b phi_{wire 23-b}( bit b of (i ^ (i>>1)) )
__global__ void k_init(float* __restrict__ st, const float* __restrict__ ws) {
    const float* C = ws + 64;    // block 0 tables
    const float* S = ws + 256;
    unsigned q = blockIdx.x * blockDim.x + threadIdx.x;   // float4 index
    unsigned i = q << 2;
    unsigned jb = i ^ (i >> 1);
    float P = 1.0f;
#pragma unroll
    for (int b = 2; b < 24; ++b) {
        int w = 23 - b;
        P *= ((jb >> b) & 1) ? S[w] : C[w];
    }
    float4 v;
    float* vv = &v.x;
#pragma unroll
    for (int d = 0; d < 4; ++d) {
        unsigned ii = i + d;
        unsigned j = ii ^ (ii >> 1);
        float f1 = ((j >> 1) & 1) ? S[22] : C[22];
        float f0 = (j & 1)        ? S[23] : C[23];
        vv[d] = P * f1 * f0;
    }
    reinterpret_cast<float4*>(st)[q] = v;
}

// ---- helpers ----------------------------------------------------------

// LDS float4-index swizzle: kills bank conflicts for every gather pattern
// used below (any 8 consecutive-f lanes stay distinct mod 8 bank-quads).
__device__ __forceinline__ unsigned sw(unsigned f) { return f ^ ((f >> 3) & 7u); }

__device__ __forceinline__ void ry2(float& a0, float& a1, float c, float s, bool ctl) {
    float w0 = c * a0 - s * a1;
    float w1 = s * a0 + c * a1;
    a0 = ctl ? w1 : w0;
    a1 = ctl ? w0 : w1;
}

// One stage on a 32-element granule x[8] (float4 each).
// Element index bits: d = bits {0,1}; j (0..7) = bits {w, w+1, w+2}.
// TB = b - w (target bit within j). MODE: 0 = ctrl from j bit TB+1,
// 1 = ctrl always true, -1 = no CNOT.
template<int TB, int MODE>
__device__ __forceinline__ void stage8(float4* x, float c, float s) {
#pragma unroll
    for (int j0 = 0; j0 < 8; ++j0) {
        if (j0 & (1 << TB)) continue;
        const int j1 = j0 | (1 << TB);
        const bool ctl = (MODE == 1) || (MODE == 0 && ((j0 >> (TB + 1)) & 1));
        ry2(x[j0].x, x[j1].x, c, s, ctl);
        ry2(x[j0].y, x[j1].y, c, s, ctl);
        ry2(x[j0].z, x[j1].z, c, s, ctl);
        ry2(x[j0].w, x[j1].w, c, s, ctl);
    }
}

// Stages S2,S1,S0 on a 16-element granule y[4]: elem bits {0,1}=d, {2,3}=j.
__device__ __forceinline__ void low4(float4* y, const float* cc, const float* sv) {
    {   // S2: tgt bit2 = j bit0, ctrl bit3 = j bit1
        float c = cc[2], s = sv[2];
        ry2(y[0].x, y[1].x, c, s, false); ry2(y[0].y, y[1].y, c, s, false);
        ry2(y[0].z, y[1].z, c, s, false); ry2(y[0].w, y[1].w, c, s, false);
        ry2(y[2].x, y[3].x, c, s, true);  ry2(y[2].y, y[3].y, c, s, true);
        ry2(y[2].z, y[3].z, c, s, true);  ry2(y[2].w, y[3].w, c, s, true);
    }
    {   // S1: tgt bit1 = d bit1, ctrl bit2 = j bit0
        float c = cc[1], s = sv[1];
#pragma unroll
        for (int j = 0; j < 4; ++j) {
            bool ctl = j & 1;
            ry2(y[j].x, y[j].z, c, s, ctl);
            ry2(y[j].y, y[j].w, c, s, ctl);
        }
    }
    {   // S0: tgt bit0 = d bit0, ctrl bit1 = d bit1
        float c = cc[0], s = sv[0];
#pragma unroll
        for (int j = 0; j < 4; ++j) {
            ry2(y[j].x, y[j].y, c, s, false);
            ry2(y[j].z, y[j].w, c, s, true);
        }
    }
}

template<int W>
__device__ __forceinline__ void gatherW(const float4* T4, unsigned tid, float4* x) {
    const unsigned lm = (1u << (W - 2)) - 1u;
    const unsigned fb = ((tid & ~lm) << 3) | (tid & lm);
#pragma unroll
    for (int j = 0; j < 8; ++j) x[j] = T4[sw(fb + (j << (W - 2)))];
}
template<int W>
__device__ __forceinline__ void scatterW(float4* T4, unsigned tid, const float4* x) {
    const unsigned lm = (1u << (W - 2)) - 1u;
    const unsigned fb = ((tid & ~lm) << 3) | (tid & lm);
#pragma unroll
    for (int j = 0; j < 8; ++j) T4[sw(fb + (j << (W - 2)))] = x[j];
}

// x = (0.6*tanh(0.1*2^23*v^2))^0.15, fast-math with small-z series
// (the exp path cancels catastrophically for z < ~1e-6).
__device__ __forceinline__ float xform(float v) {
    float z = 838860.8f * v * v;                      // GAMMA * 2^23 * v^2, >= 0
    float e2 = __builtin_amdgcn_exp2f(z * 2.8853900817779268f);   // e^(2z)
    float big = 1.0f - 2.0f * __builtin_amdgcn_rcpf(e2 + 1.0f);
    float z2 = z * z;
    float small_ = z * (1.0f - 0.33333333f * z2 * (1.0f - 0.4f * z2));
    float t = (z < 0.04f) ? small_ : big;
    return __builtin_amdgcn_exp2f(0.15f * __builtin_amdgcn_logf(0.6f * t));
}

// ---- Pass A: tile = global bits 0..13 (contiguous). blockIdx = bits 14..23.
// Stages S13 (RY(13) + CNOT(fixed bit14 = m&1, 13)), S12..S0.
__global__ __launch_bounds__(512, 4) void k_passA(float* __restrict__ st,
                                                  float* __restrict__ ws,
                                                  int k, int fuse) {
    __shared__ float4 T4[4096];   // 64 KB
    const unsigned m = blockIdx.x;
    const unsigned tid = threadIdx.x;
    const float* C = ws + 64 + k * 24;
    const float* S = ws + 256 + k * 24;
    float cc[14], sv[14];
#pragma unroll
    for (int b = 0; b < 14; ++b) { cc[b] = C[23 - b]; sv[b] = S[23 - b]; }

    float4* G4 = reinterpret_cast<float4*>(st) + (m << 12);
    float4 x[8];

    // R1: window bits {11,12,13}, gather straight from global (f = tid | j<<9)
#pragma unroll
    for (int j = 0; j < 8; ++j) x[j] = G4[tid + (j << 9)];
    if (m & 1u) stage8<2, 1>(x, cc[13], sv[13]);
    else        stage8<2,-1>(x, cc[13], sv[13]);
    stage8<1, 0>(x, cc[12], sv[12]);
    stage8<0, 0>(x, cc[11], sv[11]);
    scatterW<11>(T4, tid, x);
    __syncthreads();
    // R2: bits {9,10,11}: S10, S9
    gatherW<9>(T4, tid, x);
    stage8<1, 0>(x, cc[10], sv[10]);
    stage8<0, 0>(x, cc[9],  sv[9]);
    scatterW<9>(T4, tid, x);
    __syncthreads();
    // R3: bits {7,8,9}: S8, S7
    gatherW<7>(T4, tid, x);
    stage8<1, 0>(x, cc[8], sv[8]);
    stage8<0, 0>(x, cc[7], sv[7]);
    scatterW<7>(T4, tid, x);
    __syncthreads();
    // R4: bits {5,6,7}: S6, S5
    gatherW<5>(T4, tid, x);
    stage8<1, 0>(x, cc[6], sv[6]);
    stage8<0, 0>(x, cc[5], sv[5]);
    scatterW<5>(T4, tid, x);
    __syncthreads();
    // R5: bits {3,4,5}: S4, S3
    gatherW<3>(T4, tid, x);
    stage8<1, 0>(x, cc[4], sv[4]);
    stage8<0, 0>(x, cc[3], sv[3]);
    scatterW<3>(T4, tid, x);
    __syncthreads();
    // R6: bits {0..3}: S2,S1,S0 on two 16-elem granules; write straight to global.
    const unsigned fb0 = tid << 2;
    const unsigned fb1 = (1u << 11) | (tid << 2);
#pragma unroll
    for (int j = 0; j < 4; ++j) x[j]     = T4[sw(fb0 + j)];
#pragma unroll
    for (int j = 0; j < 4; ++j) x[4 + j] = T4[sw(fb1 + j)];
    __syncthreads();              // allows T4 reuse as reduction scratch below
    low4(&x[0], cc, sv);
    low4(&x[4], cc, sv);
    if (fuse) {
        float lsum = 0.f;
#pragma unroll
        for (int j = 0; j < 8; ++j) {
            float* v = &x[j].x;
#pragma unroll
            for (int d = 0; d < 4; ++d) { v[d] = xform(v[d]); lsum += v[d]; }
        }
#pragma unroll
        for (int j = 0; j < 4; ++j) G4[fb0 + j] = x[j];
#pragma unroll
        for (int j = 0; j < 4; ++j) G4[fb1 + j] = x[4 + j];
#pragma unroll
        for (int o = 32; o > 0; o >>= 1) lsum += __shfl_down(lsum, o, 64);
        float* wsum = reinterpret_cast<float*>(T4);
        if ((tid & 63u) == 0) wsum[tid >> 6] = lsum;
        __syncthreads();
        if (tid == 0) {
            float b = 0.f;
#pragma unroll
            for (int i = 0; i < 8; ++i) b += wsum[i];
            atomicAdd(ws, b);
        }
    } else {
#pragma unroll
        for (int j = 0; j < 4; ++j) G4[fb0 + j] = x[j];
#pragma unroll
        for (int j = 0; j < 4; ++j) G4[fb1 + j] = x[4 + j];
    }
}

// ---- Pass B: tile = global bits {0..3} u {14..23}; blockIdx m = bits 4..13.
// Local bit j: 0..3 -> global 0..3 (idle), 4..13 -> global 14..23.
// Stages (local): S13 = RY only, then S12..S4 (RY(j) + CNOT(j+1,j)).
__global__ __launch_bounds__(512, 4) void k_passB(float* __restrict__ st,
                                                  const float* __restrict__ ws, int k) {
    __shared__ float4 T4[4096];   // 64 KB
    const unsigned m = blockIdx.x;
    const unsigned tid = threadIdx.x;
    const float* C = ws + 64 + k * 24;
    const float* S = ws + 256 + k * 24;
    float cc[14], sv[14];
#pragma unroll
    for (int j = 4; j < 14; ++j) { cc[j] = C[13 - j]; sv[j] = S[13 - j]; }

    float4* G4 = reinterpret_cast<float4*>(st);
    const unsigned mb = m << 2;
    float4 x[8];

    // R1: local window bits {11,12,13}, gather straight from global.
    // local f4 f -> global f4 (f>>2)<<12 | m<<2 | (f&3)
#pragma unroll
    for (int j = 0; j < 8; ++j) {
        unsigned f = tid | (j << 9);
        x[j] = G4[((f >> 2) << 12) | mb | (f & 3u)];
    }
    stage8<2,-1>(x, cc[13], sv[13]);   // RY on local 13 (global 23), no CNOT
    stage8<1, 0>(x, cc[12], sv[12]);
    stage8<0, 0>(x, cc[11], sv[11]);
    scatterW<11>(T4, tid, x);
    __syncthreads();
    gatherW<9>(T4, tid, x);
    stage8<1, 0>(x, cc[10], sv[10]);
    stage8<0, 0>(x, cc[9],  sv[9]);
    scatterW<9>(T4, tid, x);
    __syncthreads();
    gatherW<7>(T4, tid, x);
    stage8<1, 0>(x, cc[8], sv[8]);
    stage8<0, 0>(x, cc[7], sv[7]);
    scatterW<7>(T4, tid, x);
    __syncthreads();
    gatherW<5>(T4, tid, x);
    stage8<1, 0>(x, cc[6], sv[6]);
    stage8<0, 0>(x, cc[5], sv[5]);
    scatterW<5>(T4, tid, x);
    __syncthreads();
    // R5: bits {3,4,5}: only S4 (tgt local 4, ctrl local 5; local 3 idle)
    gatherW<3>(T4, tid, x);
    stage8<1, 0>(x, cc[4], sv[4]);
    scatterW<3>(T4, tid, x);
    __syncthreads();
    // Writeback (64B global segments, 4 lanes each)
#pragma unroll
    for (int i = 0; i < 8; ++i) {
        unsigned e = tid + (i << 9);
        G4[((e >> 2) << 12) | mb | (e & 3u)] = T4[sw(e)];
    }
}

__global__ void k_final(float* __restrict__ st, const float* __restrict__ ws) {
    unsigned idx = blockIdx.x * blockDim.x + threadIdx.x;
    unsigned stride = gridDim.x * blockDim.x;
    float mean = ws[0] * (1.0f / 16777216.0f);
    float4* G4 = reinterpret_cast<float4*>(st);
    for (unsigned q = idx; q < (SSIZE / 4); q += stride) {
        float4 v = G4[q];
        v.x -= mean; v.y -= mean; v.z -= mean; v.w -= mean;
        G4[q] = v;
    }
}

extern "C" void kernel_launch(void* const* d_in, const int* in_sizes, int n_in,
                              void* d_out, int out_size, void* d_ws, size_t ws_size,
                              hipStream_t stream) {
    const float* ang = (const float*)d_in[0];   // [8][24] float32
    float* st = (float*)d_out;                  // state lives in d_out (64 MB), in place
    float* ws = (float*)d_ws;                   // sum + cos/sin tables

    k_prep<<<1, 256, 0, stream>>>(ang, ws);
    k_init<<<16384, 256, 0, stream>>>(st, ws);
    for (int k = 1; k < NB; ++k) {
        k_passB<<<1024, 512, 0, stream>>>(st, ws, k);
        k_passA<<<1024, 512, 0, stream>>>(st, ws, k, (k == NB - 1) ? 1 : 0);
    }
    k_final<<<4096, 256, 0, stream>>>(st, ws);
}

// Round 4
// 613.068 us; speedup vs baseline: 1.4821x; 1.0065x over previous
//
#include <hip/hip_runtime.h>

#define NB 8
#define SSIZE (1u << 24)

// Flat index convention (jnp reshape of (2,)*24): wire w <-> bit b = 23-w.
// Per block k: RY on all wires, then CNOT(c, c-1) for c = 23..1, applied as
// stages S_b = RY(b) + CNOT(b+1, b), descending b (RY(b) commutes with
// higher-bit CNOTs). passB handles S23(RY only)..S14 on tile bits
// {0..3}u{14..23}; passA handles S13..S0 on tile bits {0..13}.
//
// ws layout (floats): [0]=sum, [64 + k*24 + w]=cos(theta/2), [256 + ...]=sin.

__global__ void k_prep(const float* __restrict__ ang, float* __restrict__ ws) {
    int t = threadIdx.x;
    if (t == 0) ws[0] = 0.0f;
    if (t < NB * 24) {
        float a = 0.5f * ang[t];
        ws[64 + t]  = __builtin_cosf(a);
        ws[256 + t] = __builtin_sinf(a);
    }
}

// ---- helpers ----------------------------------------------------------

// LDS float4-index swizzle: col(f) = (f ^ (f>>3) ^ (f>>5)) & 7 is rank-3 on
// every per-instruction varying-address subspace used below -> <=2-way.
__device__ __forceinline__ unsigned sw(unsigned f) {
    return f ^ (((f >> 3) ^ (f >> 5)) & 7u);
}

__device__ __forceinline__ void ry2(float& a0, float& a1, float c, float s, bool ctl) {
    float w0 = c * a0 - s * a1;
    float w1 = s * a0 + c * a1;
    a0 = ctl ? w1 : w0;
    a1 = ctl ? w0 : w1;
}

// One stage on a 64-element granule x[16] (float4 each).
// Element bits: d = {0,1} (inside float4); j (0..15) = 4 window bits.
// TB = target bit within j. MODE: 0 = ctrl from j bit TB+1, 1 = ctrl always,
// -1 = no CNOT.
template<int TB, int MODE>
__device__ __forceinline__ void stage16(float4* x, float c, float s) {
#pragma unroll
    for (int j0 = 0; j0 < 16; ++j0) {
        if (j0 & (1 << TB)) continue;
        const int j1 = j0 | (1 << TB);
        const bool ctl = (MODE == 1) || (MODE == 0 && ((j0 >> (TB + 1)) & 1));
        ry2(x[j0].x, x[j1].x, c, s, ctl);
        ry2(x[j0].y, x[j1].y, c, s, ctl);
        ry2(x[j0].z, x[j1].z, c, s, ctl);
        ry2(x[j0].w, x[j1].w, c, s, ctl);
    }
}

// S1 (tgt elem bit1=d1, ctrl elem bit2 = j bit0) and S0 (tgt d0, ctrl d1).
__device__ __forceinline__ void dstages(float4* x, float c1, float s1,
                                        float c0, float s0) {
#pragma unroll
    for (int j = 0; j < 16; ++j) {
        bool ctl = j & 1;
        ry2(x[j].x, x[j].z, c1, s1, ctl);
        ry2(x[j].y, x[j].w, c1, s1, ctl);
        ry2(x[j].x, x[j].y, c0, s0, false);
        ry2(x[j].z, x[j].w, c0, s0, true);
    }
}

// x = (0.6*tanh(0.1*2^23*v^2))^0.15, fast-math; small-z series avoids
// catastrophic cancellation.
__device__ __forceinline__ float xform(float v) {
    float z = 838860.8f * v * v;
    float e2 = __builtin_amdgcn_exp2f(z * 2.8853900817779268f);   // e^(2z)
    float big = 1.0f - 2.0f * __builtin_amdgcn_rcpf(e2 + 1.0f);
    float z2 = z * z;
    float small_ = z * (1.0f - 0.33333333f * z2 * (1.0f - 0.4f * z2));
    float t = (z < 0.04f) ? small_ : big;
    return __builtin_amdgcn_exp2f(0.15f * __builtin_amdgcn_logf(0.6f * t));
}

// ---- Pass A: tile = bits 0..13 (contiguous, 64 KB). blockIdx = bits 14..23.
// R1 {10..13}: S13(ctrl=bit14=m&1),S12,S11,S10 ; R2 {7..10}: S9,S8,S7 ;
// R3 {4..7}: S6,S5,S4 ; R4 {2,3,4}+d+bit13: S3,S2,S1,S0 (+optional xform/sum).
__global__ __launch_bounds__(256, 2) void k_passA(float* __restrict__ st,
                                                  float* __restrict__ ws,
                                                  int k, int fuse) {
    __shared__ float4 T4[4096];   // 64 KB
    const unsigned m = blockIdx.x;
    const unsigned tid = threadIdx.x;
    const float* C = ws + 64 + k * 24;
    const float* S = ws + 256 + k * 24;
    float ca[14], sa[14];
#pragma unroll
    for (int b = 0; b < 14; ++b) { ca[b] = C[23 - b]; sa[b] = S[23 - b]; }

    float4* G4 = reinterpret_cast<float4*>(st) + (m << 12);
    float4 x[16];

    // R1: j = elem bits {10..13} = f bits {8..11}; fully coalesced loads.
#pragma unroll
    for (int jj = 0; jj < 16; ++jj) x[jj] = G4[tid + (jj << 8)];
    if (m & 1u) stage16<3, 1>(x, ca[13], sa[13]);
    else        stage16<3,-1>(x, ca[13], sa[13]);
    stage16<2, 0>(x, ca[12], sa[12]);
    stage16<1, 0>(x, ca[11], sa[11]);
    stage16<0, 0>(x, ca[10], sa[10]);
#pragma unroll
    for (int jj = 0; jj < 16; ++jj) T4[sw(tid | (jj << 8))] = x[jj];
    __syncthreads();
    // R2: j = elem {7..10} = f bits {5..8}
    {
        const unsigned fb = (tid & 31) | ((tid >> 5) << 9);
#pragma unroll
        for (int jj = 0; jj < 16; ++jj) x[jj] = T4[sw(fb | (jj << 5))];
        stage16<2, 0>(x, ca[9], sa[9]);
        stage16<1, 0>(x, ca[8], sa[8]);
        stage16<0, 0>(x, ca[7], sa[7]);
#pragma unroll
        for (int jj = 0; jj < 16; ++jj) T4[sw(fb | (jj << 5))] = x[jj];
    }
    __syncthreads();
    // R3: j = elem {4..7} = f bits {2..5}
    {
        const unsigned fb = (tid & 3) | ((tid >> 2) << 6);
#pragma unroll
        for (int jj = 0; jj < 16; ++jj) x[jj] = T4[sw(fb | (jj << 2))];
        stage16<2, 0>(x, ca[6], sa[6]);
        stage16<1, 0>(x, ca[5], sa[5]);
        stage16<0, 0>(x, ca[4], sa[4]);
#pragma unroll
        for (int jj = 0; jj < 16; ++jj) T4[sw(fb | (jj << 2))] = x[jj];
    }
    __syncthreads();
    // R4: j bits {0,1,2} = elem {2,3,4} (f bits {0..2}); j bit3 = f bit 11.
    {
#pragma unroll
        for (int jj = 0; jj < 16; ++jj)
            x[jj] = T4[sw((jj & 7) | (tid << 3) | ((jj >> 3) << 11))];
        stage16<1, 0>(x, ca[3], sa[3]);   // S3
        stage16<0, 0>(x, ca[2], sa[2]);   // S2
        dstages(x, ca[1], sa[1], ca[0], sa[0]);   // S1, S0
        if (fuse) {
            float lsum = 0.f;
#pragma unroll
            for (int jj = 0; jj < 16; ++jj) {
                float* v = &x[jj].x;
#pragma unroll
                for (int d = 0; d < 4; ++d) { v[d] = xform(v[d]); lsum += v[d]; }
            }
#pragma unroll
            for (int jj = 0; jj < 16; ++jj)
                G4[(jj & 7) | (tid << 3) | ((jj >> 3) << 11)] = x[jj];
#pragma unroll
            for (int o = 32; o > 0; o >>= 1) lsum += __shfl_down(lsum, o, 64);
            __syncthreads();
            float* wsum = reinterpret_cast<float*>(T4);
            if ((tid & 63u) == 0) wsum[tid >> 6] = lsum;
            __syncthreads();
            if (tid == 0)
                atomicAdd(ws, wsum[0] + wsum[1] + wsum[2] + wsum[3]);
        } else {
#pragma unroll
            for (int jj = 0; jj < 16; ++jj)
                G4[(jj & 7) | (tid << 3) | ((jj >> 3) << 11)] = x[jj];
        }
    }
}

// ---- Pass B: tile = bits {0..3}u{14..23} (64 KB); blockIdx m = bits 4..13.
// Local elem le: {0..3}=global{0..3}, {4..13}=global{14..23}. lf = le>>2.
// R1 {le10..13}=g{20..23}: S23(RY),S22,S21,S20 ; R2 {le7..10}: S19,S18,S17 ;
// R3 {le4..7}: S16,S15,S14.  init!=0: compute block-0 state analytically.
__global__ __launch_bounds__(256, 2) void k_passB(float* __restrict__ st,
                                                  const float* __restrict__ ws,
                                                  int k, int init) {
    __shared__ float4 T4[4096];   // 64 KB
    const unsigned m = blockIdx.x;
    const unsigned tid = threadIdx.x;
    const float* C = ws + 64 + k * 24;
    const float* S = ws + 256 + k * 24;
    float cg[10], sg[10];   // cg[t] for stage b = 14+t  (w = 9-t)
#pragma unroll
    for (int t = 0; t < 10; ++t) { cg[t] = C[9 - t]; sg[t] = S[9 - t]; }

    float4* G4 = reinterpret_cast<float4*>(st);
    const unsigned mb = m << 2;
    float4 x[16];

    if (init) {
        // amp(i) = prod_b phi_b(bit b of (i ^ (i>>1))), phi_b(g)= g?S0[23-b]:C0[23-b]
        // i bits: {0,1}=d, {2,3}=tid&3, {4..13}=m, {14..19}=tid>>2, {20..23}=jj
        const float* C0 = ws + 64;
        const float* S0 = ws + 256;
        unsigned t2 = tid & 3u;
        unsigned th = tid >> 2;
        float P = 1.f;
        { unsigned g = (t2 ^ (t2 >> 1)) & 1u;      P *= g ? S0[21] : C0[21]; } // g2
        { unsigned g = ((t2 >> 1) ^ m) & 1u;       P *= g ? S0[20] : C0[20]; } // g3
#pragma unroll
        for (int b = 4; b <= 12; ++b) {
            unsigned g = ((m >> (b - 4)) ^ (m >> (b - 3))) & 1u;
            P *= g ? S0[23 - b] : C0[23 - b];
        }
        { unsigned g = ((m >> 9) ^ th) & 1u;       P *= g ? S0[10] : C0[10]; } // g13
#pragma unroll
        for (int b = 14; b <= 18; ++b) {
            unsigned g = ((th >> (b - 14)) ^ (th >> (b - 13))) & 1u;
            P *= g ? S0[23 - b] : C0[23 - b];
        }
        float D[4];
#pragma unroll
        for (int d = 0; d < 4; ++d) {
            unsigned g0 = (d ^ (d >> 1)) & 1u;
            unsigned g1 = ((d >> 1) ^ t2) & 1u;
            D[d] = (g0 ? S0[23] : C0[23]) * (g1 ? S0[22] : C0[22]);
        }
        unsigned th5 = (th >> 5) & 1u;
#pragma unroll
        for (int jj = 0; jj < 16; ++jj) {
            unsigned g19 = (th5 ^ (unsigned)jj) & 1u;
            unsigned g20 = ((unsigned)jj ^ ((unsigned)jj >> 1)) & 1u;
            unsigned g21 = (((unsigned)jj >> 1) ^ ((unsigned)jj >> 2)) & 1u;
            unsigned g22 = (((unsigned)jj >> 2) ^ ((unsigned)jj >> 3)) & 1u;
            unsigned g23 = ((unsigned)jj >> 3) & 1u;
            float J = (g19 ? S0[4] : C0[4]) * (g20 ? S0[3] : C0[3]) *
                      (g21 ? S0[2] : C0[2]) * (g22 ? S0[1] : C0[1]) *
                      (g23 ? S0[0] : C0[0]);
            float PJ = P * J;
            x[jj] = make_float4(PJ * D[0], PJ * D[1], PJ * D[2], PJ * D[3]);
        }
    } else {
#pragma unroll
        for (int jj = 0; jj < 16; ++jj) {
            unsigned lf = tid | (jj << 8);
            x[jj] = G4[((lf >> 2) << 12) | mb | (lf & 3u)];
        }
    }
    stage16<3,-1>(x, cg[9], sg[9]);   // S23 (RY only)
    stage16<2, 0>(x, cg[8], sg[8]);   // S22
    stage16<1, 0>(x, cg[7], sg[7]);   // S21
    stage16<0, 0>(x, cg[6], sg[6]);   // S20
#pragma unroll
    for (int jj = 0; jj < 16; ++jj) T4[sw(tid | (jj << 8))] = x[jj];
    __syncthreads();
    {
        const unsigned fb = (tid & 31) | ((tid >> 5) << 9);
#pragma unroll
        for (int jj = 0; jj < 16; ++jj) x[jj] = T4[sw(fb | (jj << 5))];
        stage16<2, 0>(x, cg[5], sg[5]);   // S19
        stage16<1, 0>(x, cg[4], sg[4]);   // S18
        stage16<0, 0>(x, cg[3], sg[3]);   // S17
#pragma unroll
        for (int jj = 0; jj < 16; ++jj) T4[sw(fb | (jj << 5))] = x[jj];
    }
    __syncthreads();
    {
        const unsigned fb = (tid & 3) | ((tid >> 2) << 6);
#pragma unroll
        for (int jj = 0; jj < 16; ++jj) x[jj] = T4[sw(fb | (jj << 2))];
        stage16<2, 0>(x, cg[2], sg[2]);   // S16
        stage16<1, 0>(x, cg[1], sg[1]);   // S15
        stage16<0, 0>(x, cg[0], sg[0]);   // S14
#pragma unroll
        for (int jj = 0; jj < 16; ++jj) {
            unsigned lf = fb | (jj << 2);
            G4[((lf >> 2) << 12) | mb | (lf & 3u)] = x[jj];
        }
    }
}

__global__ void k_final(float* __restrict__ st, const float* __restrict__ ws) {
    unsigned idx = blockIdx.x * blockDim.x + threadIdx.x;
    unsigned stride = gridDim.x * blockDim.x;
    float mean = ws[0] * (1.0f / 16777216.0f);
    float4* G4 = reinterpret_cast<float4*>(st);
    for (unsigned q = idx; q < (SSIZE / 4); q += stride) {
        float4 v = G4[q];
        v.x -= mean; v.y -= mean; v.z -= mean; v.w -= mean;
        G4[q] = v;
    }
}

extern "C" void kernel_launch(void* const* d_in, const int* in_sizes, int n_in,
                              void* d_out, int out_size, void* d_ws, size_t ws_size,
                              hipStream_t stream) {
    const float* ang = (const float*)d_in[0];   // [8][24] float32
    float* st = (float*)d_out;                  // state in d_out, in place
    float* ws = (float*)d_ws;

    k_prep<<<1, 256, 0, stream>>>(ang, ws);
    for (int k = 1; k < NB; ++k) {
        k_passB<<<1024, 256, 0, stream>>>(st, ws, k, (k == 1) ? 1 : 0);
        k_passA<<<1024, 256, 0, stream>>>(st, ws, k, (k == NB - 1) ? 1 : 0);
    }
    k_final<<<4096, 256, 0, stream>>>(st, ws);
}

// Round 5
// 530.703 us; speedup vs baseline: 1.7122x; 1.1552x over previous
//
#include <hip/hip_runtime.h>

#define NB 8
#define SSIZE (1u << 24)

// Flat index convention (jnp reshape of (2,)*24): wire w <-> bit b = 23-w.
// Stages S_b = RY(b) + CNOT(b+1, b), applied descending b (valid since RY(b)
// commutes with higher-bit CNOTs). passB: S23(RY only)..S14 on tile bits
// {0..3}u{14..23}; passA: S13..S0 on tile bits {0..13} (S13 ctrl = bit14 = m&1).
//
// ws layout (floats): [0]=sum, [64 + k*24 + w]=cos(theta/2), [256 + ...]=sin.

__global__ void k_prep(const float* __restrict__ ang, float* __restrict__ ws) {
    int t = threadIdx.x;
    if (t == 0) ws[0] = 0.0f;
    if (t < NB * 24) {
        float a = 0.5f * ang[t];
        ws[64 + t]  = __builtin_cosf(a);
        ws[256 + t] = __builtin_sinf(a);
    }
}

// ---- helpers ----------------------------------------------------------

__device__ __forceinline__ unsigned sw(unsigned f) {
    return f ^ (((f >> 3) ^ (f >> 5)) & 7u);
}

__device__ __forceinline__ void ry2(float& a0, float& a1, float c, float s, bool ctl) {
    float w0 = c * a0 - s * a1;
    float w1 = s * a0 + c * a1;
    a0 = ctl ? w1 : w0;
    a1 = ctl ? w0 : w1;
}

// Stage on 8xfloat4 granule: elem bits {0,1}=d, {2,3,4}=register index jj.
// TB = target bit within jj. MODE: 0 = ctrl from jj bit TB+1, 1 = always, -1 = none.
template<int TB, int MODE>
__device__ __forceinline__ void stage8(float4* x, float c, float s) {
#pragma unroll
    for (int j0 = 0; j0 < 8; ++j0) {
        if (j0 & (1 << TB)) continue;
        const int j1 = j0 | (1 << TB);
        const bool ctl = (MODE == 1) || (MODE == 0 && ((j0 >> (TB + 1)) & 1));
        ry2(x[j0].x, x[j1].x, c, s, ctl);
        ry2(x[j0].y, x[j1].y, c, s, ctl);
        ry2(x[j0].z, x[j1].z, c, s, ctl);
        ry2(x[j0].w, x[j1].w, c, s, ctl);
    }
}

// Fused RY+CNOT with target bit in LANE space: result = cA*a + cP*partner.
// beta = lane's tgt bit, gamma = ctrl value:
//   g=0: (cA,cP) = (c, beta? s : -s) ; g=1: (cA,cP) = (beta? -s : s, c)
__device__ __forceinline__ void coefs(unsigned lane, int lb, bool g,
                                      float c, float s, float& cA, float& cP) {
    bool b = (lane >> lb) & 1u;
    cA = g ? (b ? -s : s) : c;
    cP = g ? c : (b ? s : -s);
}

__device__ __forceinline__ void lane_stage(float4* x, int mask, float cA, float cP) {
#pragma unroll
    for (int j = 0; j < 8; ++j) {
        float px = __shfl_xor(x[j].x, mask, 64);
        float py = __shfl_xor(x[j].y, mask, 64);
        float pz = __shfl_xor(x[j].z, mask, 64);
        float pw = __shfl_xor(x[j].w, mask, 64);
        x[j].x = cA * x[j].x + cP * px;
        x[j].y = cA * x[j].y + cP * py;
        x[j].z = cA * x[j].z + cP * pz;
        x[j].w = cA * x[j].w + cP * pw;
    }
}

// Lane-target stage whose ctrl = register-index bit 0 (two coef pairs).
__device__ __forceinline__ void lane_stage_jc(float4* x, int mask,
                                              float cA0, float cP0,
                                              float cA1, float cP1) {
#pragma unroll
    for (int j = 0; j < 8; ++j) {
        float cA = (j & 1) ? cA1 : cA0;
        float cP = (j & 1) ? cP1 : cP0;
        float px = __shfl_xor(x[j].x, mask, 64);
        float py = __shfl_xor(x[j].y, mask, 64);
        float pz = __shfl_xor(x[j].z, mask, 64);
        float pw = __shfl_xor(x[j].w, mask, 64);
        x[j].x = cA * x[j].x + cP * px;
        x[j].y = cA * x[j].y + cP * py;
        x[j].z = cA * x[j].z + cP * pz;
        x[j].w = cA * x[j].w + cP * pw;
    }
}

// S1 (tgt d1, ctrl = runtime bool g1) then S0 (tgt d0, ctrl d1).
__device__ __forceinline__ void dstages(float4* x, float c1, float s1, bool g1,
                                        float c0, float s0) {
#pragma unroll
    for (int j = 0; j < 8; ++j) {
        ry2(x[j].x, x[j].z, c1, s1, g1);
        ry2(x[j].y, x[j].w, c1, s1, g1);
        ry2(x[j].x, x[j].y, c0, s0, false);
        ry2(x[j].z, x[j].w, c0, s0, true);
    }
}

// x = (0.6*tanh(0.1*2^23*v^2))^0.15; small-z series avoids cancellation.
__device__ __forceinline__ float xform(float v) {
    float z = 838860.8f * v * v;
    float e2 = __builtin_amdgcn_exp2f(z * 2.8853900817779268f);   // e^(2z)
    float big = 1.0f - 2.0f * __builtin_amdgcn_rcpf(e2 + 1.0f);
    float z2 = z * z;
    float small_ = z * (1.0f - 0.33333333f * z2 * (1.0f - 0.4f * z2));
    float t = (z < 0.04f) ? small_ : big;
    return __builtin_amdgcn_exp2f(0.15f * __builtin_amdgcn_logf(0.6f * t));
}

// ---- Pass A: tile = bits 0..13 (64 KB). blockIdx m = bits 14..23.
// layout1: f4 f = tid | (jj<<9) -> jj = elem {11,12,13}, lane = elem {2..7},
// tid{6,7,8} = elem {8,9,10}. layout2: f = lane | (jj<<6) | ((tid>>6)<<9)
// -> jj = elem {8,9,10}, tid{6,7,8} = elem {11,12,13}.
__global__ __launch_bounds__(512, 4) void k_passA(float* __restrict__ st,
                                                  float* __restrict__ ws,
                                                  int k, int fuse) {
    __shared__ float4 T4[4096];   // 64 KB
    const unsigned m = blockIdx.x;
    const unsigned tid = threadIdx.x;
    const unsigned lane = tid & 63u;
    const float* C = ws + 64 + k * 24;
    const float* S = ws + 256 + k * 24;
    float ca[14], sa[14];
#pragma unroll
    for (int b = 0; b < 14; ++b) { ca[b] = C[23 - b]; sa[b] = S[23 - b]; }

    float4* G4 = reinterpret_cast<float4*>(st) + (m << 12);
    float4 x[8];

    // R1: coalesced load; S13 (ctrl = bit14 = m&1), S12, S11 in jj space.
#pragma unroll
    for (int jj = 0; jj < 8; ++jj) x[jj] = G4[tid + (jj << 9)];
    if (m & 1u) stage8<2, 1>(x, ca[13], sa[13]);
    else        stage8<2,-1>(x, ca[13], sa[13]);
    stage8<1, 0>(x, ca[12], sa[12]);
    stage8<0, 0>(x, ca[11], sa[11]);
#pragma unroll
    for (int jj = 0; jj < 8; ++jj) T4[sw(tid | (jj << 9))] = x[jj];
    __syncthreads();
    const unsigned hi = (tid >> 6) << 9;
#pragma unroll
    for (int jj = 0; jj < 8; ++jj) x[jj] = T4[sw(lane | (jj << 6) | hi)];
    // S10 (ctrl = elem11 = tid bit6, wave-uniform), S9, S8 in jj space.
    if (tid & 64u) stage8<2, 1>(x, ca[10], sa[10]);
    else           stage8<2,-1>(x, ca[10], sa[10]);
    stage8<1, 0>(x, ca[9], sa[9]);
    stage8<0, 0>(x, ca[8], sa[8]);
    // Lane stages S7..S2 (tgt = lane bits 5..0).
    {   // S7: ctrl = elem8 = jj bit 0
        float cA0, cP0, cA1, cP1;
        coefs(lane, 5, false, ca[7], sa[7], cA0, cP0);
        coefs(lane, 5, true,  ca[7], sa[7], cA1, cP1);
        lane_stage_jc(x, 32, cA0, cP0, cA1, cP1);
    }
    { float cA, cP; coefs(lane, 4, (lane >> 5) & 1, ca[6], sa[6], cA, cP); lane_stage(x, 16, cA, cP); }
    { float cA, cP; coefs(lane, 3, (lane >> 4) & 1, ca[5], sa[5], cA, cP); lane_stage(x,  8, cA, cP); }
    { float cA, cP; coefs(lane, 2, (lane >> 3) & 1, ca[4], sa[4], cA, cP); lane_stage(x,  4, cA, cP); }
    { float cA, cP; coefs(lane, 1, (lane >> 2) & 1, ca[3], sa[3], cA, cP); lane_stage(x,  2, cA, cP); }
    { float cA, cP; coefs(lane, 0, (lane >> 1) & 1, ca[2], sa[2], cA, cP); lane_stage(x,  1, cA, cP); }
    // d stages: S1 (ctrl = elem2 = lane bit 0), S0.
    dstages(x, ca[1], sa[1], lane & 1u, ca[0], sa[0]);

    if (fuse) {
        float lsum = 0.f;
#pragma unroll
        for (int jj = 0; jj < 8; ++jj) {
            float* v = &x[jj].x;
#pragma unroll
            for (int d = 0; d < 4; ++d) { v[d] = xform(v[d]); lsum += v[d]; }
        }
#pragma unroll
        for (int jj = 0; jj < 8; ++jj) G4[lane | (jj << 6) | hi] = x[jj];
#pragma unroll
        for (int o = 32; o > 0; o >>= 1) lsum += __shfl_down(lsum, o, 64);
        __syncthreads();
        float* wsum = reinterpret_cast<float*>(T4);
        if ((tid & 63u) == 0) wsum[tid >> 6] = lsum;
        __syncthreads();
        if (tid == 0) {
            float b = 0.f;
#pragma unroll
            for (int i = 0; i < 8; ++i) b += wsum[i];
            atomicAdd(ws, b);
        }
    } else {
#pragma unroll
        for (int jj = 0; jj < 8; ++jj) G4[lane | (jj << 6) | hi] = x[jj];
    }
}

// ---- Pass B: tile = bits {0..3}u{14..23} (64 KB); blockIdx m = bits 4..13.
// Local f4 lf: lf{0,1}=g{2,3}, lf{2..11}=g{14..23}; global f4
// gf = (lf&3) | (m<<2) | ((lf>>2)<<12).
// layout1: lf = tid | (jj<<9): jj = g{21,22,23}, lane = g{2,3,14..17},
// tid{6,7,8} = g{18,19,20}. layout2: lf = lane | (jj<<6) | ((tid>>6)<<9):
// jj = g{18,19,20}, tid{6,7,8} = g{21,22,23}.
__global__ __launch_bounds__(512, 4) void k_passB(float* __restrict__ st,
                                                  const float* __restrict__ ws,
                                                  int k, int init) {
    __shared__ float4 T4[4096];   // 64 KB
    const unsigned m = blockIdx.x;
    const unsigned tid = threadIdx.x;
    const unsigned lane = tid & 63u;
    const float* C = ws + 64 + k * 24;
    const float* S = ws + 256 + k * 24;
    float cg[10], sg[10];   // cg[t] for stage b = 14+t (wire 9-t)
#pragma unroll
    for (int t = 0; t < 10; ++t) { cg[t] = C[9 - t]; sg[t] = S[9 - t]; }

    float4* G4 = reinterpret_cast<float4*>(st);
    const unsigned mb = m << 2;
    float4 x[8];

    if (init) {
        // Block-0 state analytic: amp(i) = prod_b phi_b(gray bit b),
        // gray = i ^ (i>>1), phi_b(g) = g ? S0[23-b] : C0[23-b].
        // i bits: d{0,1}=g0,1; tid{0,1}=g2,3; m=g{4..13}; tid{2..8}=g{14..20};
        // jj=g{21,22,23}.
        const float* C0 = ws + 64;
        const float* S0 = ws + 256;
        float P = 1.f;
        { unsigned g = (tid ^ (tid >> 1)) & 1u;        P *= g ? S0[21] : C0[21]; } // b2
        { unsigned g = ((tid >> 1) ^ m) & 1u;          P *= g ? S0[20] : C0[20]; } // b3
#pragma unroll
        for (int b = 4; b <= 12; ++b) {                                            // b4..12
            unsigned g = ((m >> (b - 4)) ^ (m >> (b - 3))) & 1u;
            P *= g ? S0[23 - b] : C0[23 - b];
        }
        { unsigned g = ((m >> 9) ^ (tid >> 2)) & 1u;   P *= g ? S0[10] : C0[10]; } // b13
#pragma unroll
        for (int b = 14; b <= 19; ++b) {                                           // b14..19
            unsigned g = ((tid >> (b - 12)) ^ (tid >> (b - 11))) & 1u;
            P *= g ? S0[23 - b] : C0[23 - b];
        }
        float D[4];
#pragma unroll
        for (int d = 0; d < 4; ++d) {
            unsigned g0 = (d ^ (d >> 1)) & 1u;
            unsigned g1 = ((d >> 1) ^ tid) & 1u;
            D[d] = (g0 ? S0[23] : C0[23]) * (g1 ? S0[22] : C0[22]);
        }
        unsigned t8 = (tid >> 8) & 1u;
#pragma unroll
        for (int jj = 0; jj < 8; ++jj) {
            unsigned g20 = (t8 ^ (unsigned)jj) & 1u;
            unsigned g21 = ((unsigned)jj ^ ((unsigned)jj >> 1)) & 1u;
            unsigned g22 = (((unsigned)jj >> 1) ^ ((unsigned)jj >> 2)) & 1u;
            unsigned g23 = (((unsigned)jj >> 2)) & 1u;
            float J = (g20 ? S0[3] : C0[3]) * (g21 ? S0[2] : C0[2]) *
                      (g22 ? S0[1] : C0[1]) * (g23 ? S0[0] : C0[0]);
            float PJ = P * J;
            x[jj] = make_float4(PJ * D[0], PJ * D[1], PJ * D[2], PJ * D[3]);
        }
    } else {
#pragma unroll
        for (int jj = 0; jj < 8; ++jj) {
            unsigned lf = tid | (jj << 9);
            x[jj] = G4[(lf & 3u) | mb | ((lf >> 2) << 12)];
        }
    }
    // S23 (RY only), S22, S21 in jj space.
    stage8<2,-1>(x, cg[9], sg[9]);
    stage8<1, 0>(x, cg[8], sg[8]);
    stage8<0, 0>(x, cg[7], sg[7]);
#pragma unroll
    for (int jj = 0; jj < 8; ++jj) T4[sw(tid | (jj << 9))] = x[jj];
    __syncthreads();
    const unsigned hi = (tid >> 6) << 9;
#pragma unroll
    for (int jj = 0; jj < 8; ++jj) x[jj] = T4[sw(lane | (jj << 6) | hi)];
    // S20 (ctrl = g21 = tid bit6, wave-uniform), S19, S18 in jj space.
    if (tid & 64u) stage8<2, 1>(x, cg[6], sg[6]);
    else           stage8<2,-1>(x, cg[6], sg[6]);
    stage8<1, 0>(x, cg[5], sg[5]);
    stage8<0, 0>(x, cg[4], sg[4]);
    // Lane stages S17..S14 (tgt g17..g14 = lane bits 5..2).
    {   // S17: ctrl = g18 = jj bit 0
        float cA0, cP0, cA1, cP1;
        coefs(lane, 5, false, cg[3], sg[3], cA0, cP0);
        coefs(lane, 5, true,  cg[3], sg[3], cA1, cP1);
        lane_stage_jc(x, 32, cA0, cP0, cA1, cP1);
    }
    { float cA, cP; coefs(lane, 4, (lane >> 5) & 1, cg[2], sg[2], cA, cP); lane_stage(x, 16, cA, cP); }
    { float cA, cP; coefs(lane, 3, (lane >> 4) & 1, cg[1], sg[1], cA, cP); lane_stage(x,  8, cA, cP); }
    { float cA, cP; coefs(lane, 2, (lane >> 3) & 1, cg[0], sg[0], cA, cP); lane_stage(x,  4, cA, cP); }
    // Writeback from layout2 (64 B global segments).
#pragma unroll
    for (int jj = 0; jj < 8; ++jj) {
        unsigned lf = lane | (jj << 6) | hi;
        G4[(lf & 3u) | mb | ((lf >> 2) << 12)] = x[jj];
    }
}

__global__ void k_final(float* __restrict__ st, const float* __restrict__ ws) {
    unsigned idx = blockIdx.x * blockDim.x + threadIdx.x;
    unsigned stride = gridDim.x * blockDim.x;
    float mean = ws[0] * (1.0f / 16777216.0f);
    float4* G4 = reinterpret_cast<float4*>(st);
    for (unsigned q = idx; q < (SSIZE / 4); q += stride) {
        float4 v = G4[q];
        v.x -= mean; v.y -= mean; v.z -= mean; v.w -= mean;
        G4[q] = v;
    }
}

extern "C" void kernel_launch(void* const* d_in, const int* in_sizes, int n_in,
                              void* d_out, int out_size, void* d_ws, size_t ws_size,
                              hipStream_t stream) {
    const float* ang = (const float*)d_in[0];   // [8][24] float32
    float* st = (float*)d_out;                  // state in d_out, in place
    float* ws = (float*)d_ws;

    k_prep<<<1, 256, 0, stream>>>(ang, ws);
    for (int k = 1; k < NB; ++k) {
        k_passB<<<1024, 512, 0, stream>>>(st, ws, k, (k == 1) ? 1 : 0);
        k_passA<<<1024, 512, 0, stream>>>(st, ws, k, (k == NB - 1) ? 1 : 0);
    }
    k_final<<<4096, 256, 0, stream>>>(st, ws);
}